// Round 4
// baseline (216.895 us; speedup 1.0000x reference)
//
#include <hip/hip_runtime.h>
#include <math.h>

#define BATCH 16384
#define NSETS 1024
#define ALPHA 0.001f
#define BETA  0.001f

// MFMA GEMM tile: 128x128 block, BK=64, 256 threads (4 waves, 2x2 wave grid,
// each wave 64x64 = 4x4 grid of 16x16x32 bf16 MFMA tiles, 2 k-steps per iter)
#define BM 128
#define BN 128
#define BK 64
#define GEMM_BLOCKS (NSETS / BN * BATCH / BM)   // 1024

typedef __attribute__((ext_vector_type(4))) float f32x4;
typedef __attribute__((ext_vector_type(8))) __bf16 bf16x8;

// ws float-index layout:
//   [0] mr_sum (atomic)    [1] completion counter (uint)   [2..3] pad
//   [4 .. 4+16384)         row sums (atomic, zeroed by bce kernel)
//   [16388 .. 16388+2048)  bce per-block partials (write-once, no zero needed)
// ws byte layout:
//   [131072 ..)            pred_bf16 (BATCH*NSETS ushort = 33.5 MB)
//   [131072 + 33554432 ..) moeb_bf16 (NSETS*NSETS ushort = 2 MB)
#define ROWSUM_OFF 4
#define BCEP_OFF   16388
#define WS_PREDBF_OFF 131072
#define WS_MOEBBF_OFF (131072 + BATCH * NSETS * 2)

__device__ __forceinline__ unsigned short f2bf(float x) {
    unsigned int u = __builtin_bit_cast(unsigned int, x);
    u = (u + 0x7FFFu + ((u >> 16) & 1u)) >> 16;   // RNE (no NaN inputs here)
    return (unsigned short)u;
}

__device__ __forceinline__ void gld16(const void* g, void* l) {
    __builtin_amdgcn_global_load_lds(
        (const __attribute__((address_space(1))) unsigned int*)g,
        (__attribute__((address_space(3))) unsigned int*)l, 16, 0, 0);
}

__device__ __forceinline__ float block_reduce_sum(float v, float* sm) {
    #pragma unroll
    for (int off = 32; off > 0; off >>= 1) v += __shfl_down(v, off, 64);
    const int lane = threadIdx.x & 63;
    const int wid  = threadIdx.x >> 6;
    if (lane == 0) sm[wid] = v;
    __syncthreads();
    const int nw = blockDim.x >> 6;
    v = (threadIdx.x < nw) ? sm[threadIdx.x] : 0.0f;
    if (wid == 0) {
        #pragma unroll
        for (int off = 32; off > 0; off >>= 1) v += __shfl_down(v, off, 64);
    }
    return v;  // valid in thread 0
}

// -------- BCE (+ pred->bf16 convert + accumulator zeroing; blocks >= 2048
// convert moebius). Replaces the memset node: zeroes mr/counter/rowsums.
__global__ __launch_bounds__(256)
void bce_convert_kernel(const float* __restrict__ pred,
                        const float* __restrict__ membership,
                        const int*   __restrict__ tidx,
                        const float* __restrict__ moeb,
                        float*       __restrict__ ws,
                        unsigned short* __restrict__ pred_bf,
                        unsigned short* __restrict__ moeb_bf) {
    const int tid = threadIdx.x;
    const int bi  = blockIdx.x;
    if (bi >= 2048) {   // moebius fp32->bf16: 64 blocks, 16 float4/thread
        const int base = (bi - 2048) * 4096 + tid;
        #pragma unroll
        for (int k = 0; k < 16; k++) {
            const int i = base + k * 256;
            const float4 v = ((const float4*)moeb)[i];
            ushort4 u;
            u.x = f2bf(v.x); u.y = f2bf(v.y); u.z = f2bf(v.z); u.w = f2bf(v.w);
            ((ushort4*)moeb_bf)[i] = u;
        }
        return;
    }
    // zero accumulators for the masses kernel (graph edge orders it)
    if (tid < 8)                 ws[ROWSUM_OFF + bi * 8 + tid] = 0.0f;
    if (bi == 0 && tid >= 8 && tid < 12) ws[tid - 8] = 0.0f;

    __shared__ float sm[4];
    const float eps = 1e-7f;
    const float hi  = 1.0f - 1e-7f;
    float acc = 0.0f;
    const int base = bi * 256 + tid;          // 0..524287
    #pragma unroll
    for (int k = 0; k < 8; k++) {             // N4 = 4194304 = 8 * 524288
        const int i  = base + k * 524288;
        const int b  = i >> 8;                // row (256 float4 per row)
        const int s4 = i & 255;
        const float4 p4 = ((const float4*)pred)[i];
        const int cls   = tidx[b];
        const float4 t4 = ((const float4*)membership)[(cls << 8) + s4];
        float cp[4];
        cp[0] = fminf(fmaxf(p4.x, eps), hi);
        cp[1] = fminf(fmaxf(p4.y, eps), hi);
        cp[2] = fminf(fmaxf(p4.z, eps), hi);
        cp[3] = fminf(fmaxf(p4.w, eps), hi);
        ushort4 u;
        u.x = f2bf(cp[0]); u.y = f2bf(cp[1]); u.z = f2bf(cp[2]); u.w = f2bf(cp[3]);
        ((ushort4*)pred_bf)[i] = u;
        const float ts[4] = {t4.x, t4.y, t4.z, t4.w};
        #pragma unroll
        for (int j = 0; j < 4; j++) {
            const float lp = __logf(cp[j]);
            const float lq = __logf(1.0f - cp[j]);
            acc += (ts[j] > 0.5f) ? lp : lq;
        }
    }
    const float tot = block_reduce_sum(acc, sm);
    if (tid == 0) ws[BCEP_OFF + bi] = tot;    // write-once partial
}

// -------- masses = p_bf16 @ moeb_bf16^T via MFMA; fused relu(-m) and row
// sums; LAST block finalizes all four losses (replaces the finalize node).
// LDS layout: 16B chunk (row r, k-subchunk k8) stored at slot 8*r + (k8^(r&7))
// (global-side swizzle; gld16 forces LDS dest = base + lane*16, so banks are
// balanced by permuting the GLOBAL source instead: 8 phases x 8 lanes = b128 min)
__global__ __launch_bounds__(256)
void masses_mfma_kernel(const unsigned short* __restrict__ A,   // pred_bf [BATCH, NSETS]
                        const unsigned short* __restrict__ Bm,  // moeb_bf [NSETS, NSETS]
                        float* __restrict__ ws,
                        float* __restrict__ out) {
    __shared__ __align__(16) unsigned short Alds[BM * BK];  // 16 KB
    __shared__ __align__(16) unsigned short Blds[BN * BK];  // 16 KB
    __shared__ float rowacc[BM];
    __shared__ float sm[4];
    __shared__ unsigned am_last;

    const int tid  = threadIdx.x;
    const int lane = tid & 63;
    const int w    = tid >> 6;
    const int wm   = w >> 1;
    const int wn   = w & 1;
    const int lr   = lane & 15;
    const int q    = lane >> 4;
    const int m0   = blockIdx.y * BM;
    const int n0   = blockIdx.x * BN;

    if (tid < BM) rowacc[tid] = 0.0f;

    f32x4 acc[4][4];
    #pragma unroll
    for (int i = 0; i < 4; i++)
        #pragma unroll
        for (int j = 0; j < 4; j++) acc[i][j] = (f32x4){0.f, 0.f, 0.f, 0.f};

    // staging: 1024 chunks of 16B per tile; thread t covers slots t+j*256.
    // slot s -> row r=s>>3, stored k8' = s&7, global k8 = k8' ^ (r&7)
    size_t aoff[4], boff[4];
    unsigned short *lA[4], *lB[4];
    #pragma unroll
    for (int j = 0; j < 4; j++) {
        const int s   = tid + j * 256;
        const int r   = s >> 3;
        const int gk8 = (s & 7) ^ (r & 7);
        aoff[j] = (size_t)(m0 + r) * NSETS + gk8 * 8;
        boff[j] = (size_t)(n0 + r) * NSETS + gk8 * 8;
        lA[j] = &Alds[s * 8];
        lB[j] = &Blds[s * 8];
    }
    const int sw = lr & 7;  // fragment-read swizzle term

    for (int k0 = 0; k0 < NSETS; k0 += BK) {
        #pragma unroll
        for (int j = 0; j < 4; j++) {
            gld16(A  + aoff[j] + k0, lA[j]);
            gld16(Bm + boff[j] + k0, lB[j]);
        }
        __syncthreads();

        #pragma unroll
        for (int h = 0; h < 2; h++) {
            bf16x8 a[4], b[4];
            const int hq = h * 4 + q;
            #pragma unroll
            for (int mi = 0; mi < 4; mi++)
                a[mi] = *(const bf16x8*)&Alds[(wm * 64 + mi * 16 + lr) * BK + 8 * (hq ^ sw)];
            #pragma unroll
            for (int ni = 0; ni < 4; ni++)
                b[ni] = *(const bf16x8*)&Blds[(wn * 64 + ni * 16 + lr) * BK + 8 * (hq ^ sw)];
            #pragma unroll
            for (int mi = 0; mi < 4; mi++)
                #pragma unroll
                for (int ni = 0; ni < 4; ni++)
                    acc[mi][ni] = __builtin_amdgcn_mfma_f32_16x16x32_bf16(
                        a[mi], b[ni], acc[mi][ni], 0, 0, 0);
        }
        __syncthreads();
    }

    // Epilogue. C/D layout: col = lane&15, row_in_tile = q*4 + r
    float mrpart = 0.0f;
    float rs[4][4];
    #pragma unroll
    for (int mi = 0; mi < 4; mi++)
        #pragma unroll
        for (int r = 0; r < 4; r++) rs[mi][r] = 0.0f;
    #pragma unroll
    for (int mi = 0; mi < 4; mi++)
        #pragma unroll
        for (int ni = 0; ni < 4; ni++)
            #pragma unroll
            for (int r = 0; r < 4; r++) {
                const float m = acc[mi][ni][r];
                mrpart    += fmaxf(-m, 0.0f);
                rs[mi][r] += m;
            }
    #pragma unroll
    for (int mi = 0; mi < 4; mi++)
        #pragma unroll
        for (int r = 0; r < 4; r++) {
            float v = rs[mi][r];
            #pragma unroll
            for (int off = 1; off < 16; off <<= 1) v += __shfl_xor(v, off, 16);
            if (lr == 0)
                atomicAdd(&rowacc[wm * 64 + mi * 16 + q * 4 + r], v);
        }

    const float mrtot = block_reduce_sum(mrpart, sm);  // has a barrier inside
    if (tid == 0) atomicAdd(&ws[0], mrtot);
    __syncthreads();   // rowacc complete
    if (tid < BM) atomicAdd(&ws[ROWSUM_OFF + m0 + tid], rowacc[tid]);

    // ---- last-block finalize (CUB threadFenceReduction pattern) ----
    __threadfence();   // drain this thread's global atomics to device scope
    __syncthreads();
    if (tid == 0)
        am_last = (atomicAdd((unsigned int*)&ws[1], 1u) == GEMM_BLOCKS - 1);
    __syncthreads();
    if (am_last) {
        __threadfence();   // acquire: other blocks' atomics now visible
        float s_ms = 0.0f;
        #pragma unroll
        for (int k = 0; k < 16; k++) {   // 16384 rowsums = 4096 f4
            const float4 v = ((const float4*)(ws + ROWSUM_OFF))[tid + k * 256];
            s_ms += fabsf(v.x - 1.0f) + fabsf(v.y - 1.0f) +
                    fabsf(v.z - 1.0f) + fabsf(v.w - 1.0f);
        }
        float s_bce = 0.0f;
        #pragma unroll
        for (int k = 0; k < 2; k++) {    // 2048 partials = 512 f4
            const float4 v = ((const float4*)(ws + BCEP_OFF))[tid + k * 256];
            s_bce += v.x + v.y + v.z + v.w;
        }
        __syncthreads();                 // sm reuse guard
        const float mssum = block_reduce_sum(s_ms, sm);
        __syncthreads();
        const float bcesum = block_reduce_sum(s_bce, sm);
        if (tid == 0) {
            const float inv = 1.0f / ((float)BATCH * (float)NSETS);
            const float bce = -bcesum * inv;
            const float mr  =  ws[0] * inv;
            const float ms  =  mssum / (float)BATCH;
            out[0] = bce + ALPHA * mr + BETA * ms;
            out[1] = bce;
            out[2] = mr;
            out[3] = ms;
        }
    }
}

extern "C" void kernel_launch(void* const* d_in, const int* in_sizes, int n_in,
                              void* d_out, int out_size, void* d_ws, size_t ws_size,
                              hipStream_t stream) {
    const float* pred       = (const float*)d_in[0];
    const float* membership = (const float*)d_in[1];
    const float* moebius    = (const float*)d_in[2];
    const int*   tidx       = (const int*)d_in[3];
    float* out = (float*)d_out;
    float* ws  = (float*)d_ws;
    unsigned short* pred_bf = (unsigned short*)((char*)d_ws + WS_PREDBF_OFF);
    unsigned short* moeb_bf = (unsigned short*)((char*)d_ws + WS_MOEBBF_OFF);

    bce_convert_kernel<<<2048 + 64, 256, 0, stream>>>(
        pred, membership, tidx, moebius, ws, pred_bf, moeb_bf);
    masses_mfma_kernel<<<dim3(NSETS / BN, BATCH / BM), 256, 0, stream>>>(
        pred_bf, moeb_bf, ws, out);
}

// Round 5
// 174.379 us; speedup vs baseline: 1.2438x; 1.2438x over previous
//
#include <hip/hip_runtime.h>
#include <math.h>

#define BATCH 16384
#define NSETS 1024
#define ALPHA 0.001f
#define BETA  0.001f

// MFMA GEMM tile: 128x128 block, BK=64, 256 threads (4 waves, 2x2 wave grid,
// each wave 64x64 = 4x4 grid of 16x16x32 bf16 MFMA tiles, 2 k-steps per iter)
#define BM 128
#define BN 128
#define BK 64
#define GEMM_BLOCKS (NSETS / BN * BATCH / BM)   // 1024

typedef __attribute__((ext_vector_type(4))) float f32x4;
typedef __attribute__((ext_vector_type(8))) __bf16 bf16x8;

// ws float-index layout:
//   [0] mr_sum (device-scope atomic)  [1] completion counter (uint)  [2..3] pad
//   [4 .. 4+16384)         row sums (device-scope atomics, zeroed by bce kernel)
//   [16388 .. 16388+2048)  bce per-block partials (write-once by prev dispatch)
// ws byte layout:
//   [131072 ..)            pred_bf16 (BATCH*NSETS ushort = 33.5 MB)
//   [131072 + 33554432 ..) moeb_bf16 (NSETS*NSETS ushort = 2 MB)
#define ROWSUM_OFF 4
#define BCEP_OFF   16388
#define WS_PREDBF_OFF 131072
#define WS_MOEBBF_OFF (131072 + BATCH * NSETS * 2)

__device__ __forceinline__ unsigned short f2bf(float x) {
    unsigned int u = __builtin_bit_cast(unsigned int, x);
    u = (u + 0x7FFFu + ((u >> 16) & 1u)) >> 16;   // RNE (no NaN inputs here)
    return (unsigned short)u;
}

__device__ __forceinline__ void gld16(const void* g, void* l) {
    __builtin_amdgcn_global_load_lds(
        (const __attribute__((address_space(1))) unsigned int*)g,
        (__attribute__((address_space(3))) unsigned int*)l, 16, 0, 0);
}

// relaxed agent-scope load: sc0/sc1 bits bypass the (stale) L1/L2, NO cache
// invalidate instruction (the fence-based path cost 2x kernel time in R4)
__device__ __forceinline__ float coh_load(const float* p) {
    return __hip_atomic_load(p, __ATOMIC_RELAXED, __HIP_MEMORY_SCOPE_AGENT);
}

__device__ __forceinline__ float block_reduce_sum(float v, float* sm) {
    #pragma unroll
    for (int off = 32; off > 0; off >>= 1) v += __shfl_down(v, off, 64);
    const int lane = threadIdx.x & 63;
    const int wid  = threadIdx.x >> 6;
    if (lane == 0) sm[wid] = v;
    __syncthreads();
    const int nw = blockDim.x >> 6;
    v = (threadIdx.x < nw) ? sm[threadIdx.x] : 0.0f;
    if (wid == 0) {
        #pragma unroll
        for (int off = 32; off > 0; off >>= 1) v += __shfl_down(v, off, 64);
    }
    return v;  // valid in thread 0
}

// -------- BCE (+ pred->bf16 convert + accumulator zeroing; blocks >= 2048
// convert moebius). Replaces the memset node: zeroes mr/counter/rowsums.
__global__ __launch_bounds__(256)
void bce_convert_kernel(const float* __restrict__ pred,
                        const float* __restrict__ membership,
                        const int*   __restrict__ tidx,
                        const float* __restrict__ moeb,
                        float*       __restrict__ ws,
                        unsigned short* __restrict__ pred_bf,
                        unsigned short* __restrict__ moeb_bf) {
    const int tid = threadIdx.x;
    const int bi  = blockIdx.x;
    if (bi >= 2048) {   // moebius fp32->bf16: 64 blocks, 16 float4/thread
        const int base = (bi - 2048) * 4096 + tid;
        #pragma unroll
        for (int k = 0; k < 16; k++) {
            const int i = base + k * 256;
            const float4 v = ((const float4*)moeb)[i];
            ushort4 u;
            u.x = f2bf(v.x); u.y = f2bf(v.y); u.z = f2bf(v.z); u.w = f2bf(v.w);
            ((ushort4*)moeb_bf)[i] = u;
        }
        return;
    }
    // zero accumulators for the masses kernel (stream order guarantees it)
    if (tid < 8)                         ws[ROWSUM_OFF + bi * 8 + tid] = 0.0f;
    if (bi == 0 && tid >= 8 && tid < 12) ws[tid - 8] = 0.0f;

    __shared__ float sm[4];
    const float eps = 1e-7f;
    const float hi  = 1.0f - 1e-7f;
    float acc = 0.0f;
    const int base = bi * 256 + tid;          // 0..524287
    #pragma unroll
    for (int k = 0; k < 8; k++) {             // N4 = 4194304 = 8 * 524288
        const int i  = base + k * 524288;
        const int b  = i >> 8;                // row (256 float4 per row)
        const int s4 = i & 255;
        const float4 p4 = ((const float4*)pred)[i];
        const int cls   = tidx[b];
        const float4 t4 = ((const float4*)membership)[(cls << 8) + s4];
        float cp[4];
        cp[0] = fminf(fmaxf(p4.x, eps), hi);
        cp[1] = fminf(fmaxf(p4.y, eps), hi);
        cp[2] = fminf(fmaxf(p4.z, eps), hi);
        cp[3] = fminf(fmaxf(p4.w, eps), hi);
        ushort4 u;
        u.x = f2bf(cp[0]); u.y = f2bf(cp[1]); u.z = f2bf(cp[2]); u.w = f2bf(cp[3]);
        ((ushort4*)pred_bf)[i] = u;
        const float ts[4] = {t4.x, t4.y, t4.z, t4.w};
        #pragma unroll
        for (int j = 0; j < 4; j++) {
            // one transcendental per element: select the log argument first
            const float x = (ts[j] > 0.5f) ? cp[j] : (1.0f - cp[j]);
            acc += __logf(x);
        }
    }
    const float tot = block_reduce_sum(acc, sm);
    if (tid == 0) ws[BCEP_OFF + bi] = tot;    // write-once partial
}

// -------- masses = p_bf16 @ moeb_bf16^T via MFMA; fused relu(-m) and row
// sums; LAST block finalizes (fence-free: all cross-block data moves via
// device-scope atomics; readers use relaxed agent-scope atomic loads).
// LDS layout: 16B chunk (row r, k-subchunk k8) stored at slot 8*r + (k8^(r&7))
// (global-side swizzle; gld16 forces LDS dest = base + lane*16, so banks are
// balanced by permuting the GLOBAL source instead: 8 phases x 8 lanes = b128 min)
__global__ __launch_bounds__(256)
void masses_mfma_kernel(const unsigned short* __restrict__ A,   // pred_bf [BATCH, NSETS]
                        const unsigned short* __restrict__ Bm,  // moeb_bf [NSETS, NSETS]
                        float* __restrict__ ws,
                        float* __restrict__ out) {
    __shared__ __align__(16) unsigned short Alds[BM * BK];  // 16 KB
    __shared__ __align__(16) unsigned short Blds[BN * BK];  // 16 KB
    __shared__ float rowacc[BM];
    __shared__ float sm[4];
    __shared__ unsigned am_last;

    const int tid  = threadIdx.x;
    const int lane = tid & 63;
    const int w    = tid >> 6;
    const int wm   = w >> 1;
    const int wn   = w & 1;
    const int lr   = lane & 15;
    const int q    = lane >> 4;
    const int m0   = blockIdx.y * BM;
    const int n0   = blockIdx.x * BN;

    if (tid < BM) rowacc[tid] = 0.0f;

    f32x4 acc[4][4];
    #pragma unroll
    for (int i = 0; i < 4; i++)
        #pragma unroll
        for (int j = 0; j < 4; j++) acc[i][j] = (f32x4){0.f, 0.f, 0.f, 0.f};

    // staging: 1024 chunks of 16B per tile; thread t covers slots t+j*256.
    // slot s -> row r=s>>3, stored k8' = s&7, global k8 = k8' ^ (r&7)
    size_t aoff[4], boff[4];
    unsigned short *lA[4], *lB[4];
    #pragma unroll
    for (int j = 0; j < 4; j++) {
        const int s   = tid + j * 256;
        const int r   = s >> 3;
        const int gk8 = (s & 7) ^ (r & 7);
        aoff[j] = (size_t)(m0 + r) * NSETS + gk8 * 8;
        boff[j] = (size_t)(n0 + r) * NSETS + gk8 * 8;
        lA[j] = &Alds[s * 8];
        lB[j] = &Blds[s * 8];
    }
    const int sw = lr & 7;  // fragment-read swizzle term

    for (int k0 = 0; k0 < NSETS; k0 += BK) {
        #pragma unroll
        for (int j = 0; j < 4; j++) {
            gld16(A  + aoff[j] + k0, lA[j]);
            gld16(Bm + boff[j] + k0, lB[j]);
        }
        __syncthreads();

        #pragma unroll
        for (int h = 0; h < 2; h++) {
            bf16x8 a[4], b[4];
            const int hq = h * 4 + q;
            #pragma unroll
            for (int mi = 0; mi < 4; mi++)
                a[mi] = *(const bf16x8*)&Alds[(wm * 64 + mi * 16 + lr) * BK + 8 * (hq ^ sw)];
            #pragma unroll
            for (int ni = 0; ni < 4; ni++)
                b[ni] = *(const bf16x8*)&Blds[(wn * 64 + ni * 16 + lr) * BK + 8 * (hq ^ sw)];
            #pragma unroll
            for (int mi = 0; mi < 4; mi++)
                #pragma unroll
                for (int ni = 0; ni < 4; ni++)
                    acc[mi][ni] = __builtin_amdgcn_mfma_f32_16x16x32_bf16(
                        a[mi], b[ni], acc[mi][ni], 0, 0, 0);
        }
        __syncthreads();
    }

    // Epilogue. C/D layout: col = lane&15, row_in_tile = q*4 + r
    float mrpart = 0.0f;
    float rs[4][4];
    #pragma unroll
    for (int mi = 0; mi < 4; mi++)
        #pragma unroll
        for (int r = 0; r < 4; r++) rs[mi][r] = 0.0f;
    #pragma unroll
    for (int mi = 0; mi < 4; mi++)
        #pragma unroll
        for (int ni = 0; ni < 4; ni++)
            #pragma unroll
            for (int r = 0; r < 4; r++) {
                const float m = acc[mi][ni][r];
                mrpart    += fmaxf(-m, 0.0f);
                rs[mi][r] += m;
            }
    #pragma unroll
    for (int mi = 0; mi < 4; mi++)
        #pragma unroll
        for (int r = 0; r < 4; r++) {
            float v = rs[mi][r];
            #pragma unroll
            for (int off = 1; off < 16; off <<= 1) v += __shfl_xor(v, off, 16);
            if (lr == 0)
                atomicAdd(&rowacc[wm * 64 + mi * 16 + q * 4 + r], v);
        }

    const float mrtot = block_reduce_sum(mrpart, sm);  // has a barrier inside
    if (tid == 0) atomicAdd(&ws[0], mrtot);            // device-scope atomic
    __syncthreads();   // rowacc complete
    if (tid < BM) atomicAdd(&ws[ROWSUM_OFF + m0 + tid], rowacc[tid]);

    // ---- fence-free last-block finalize ----
    // __syncthreads drains vmcnt(0) per wave, so every row-sum/mr atomic from
    // this block has completed at the coherent point before the counter bump.
    __syncthreads();
    if (tid == 0)
        am_last = (__hip_atomic_fetch_add((unsigned int*)&ws[1], 1u,
                       __ATOMIC_RELAXED, __HIP_MEMORY_SCOPE_AGENT)
                   == GEMM_BLOCKS - 1);
    __syncthreads();
    if (am_last) {
        float s_ms = 0.0f;
        #pragma unroll
        for (int k = 0; k < 64; k++) {   // 16384 rowsums, coherent scalar loads
            const float v = coh_load(ws + ROWSUM_OFF + tid + k * 256);
            s_ms += fabsf(v - 1.0f);
        }
        float s_bce = 0.0f;
        #pragma unroll
        for (int k = 0; k < 2; k++) {    // prev-dispatch data: plain loads OK
            const float4 v = ((const float4*)(ws + BCEP_OFF))[tid + k * 256];
            s_bce += v.x + v.y + v.z + v.w;
        }
        __syncthreads();                 // sm reuse guard
        const float mssum = block_reduce_sum(s_ms, sm);
        __syncthreads();
        const float bcesum = block_reduce_sum(s_bce, sm);
        if (tid == 0) {
            const float inv = 1.0f / ((float)BATCH * (float)NSETS);
            const float bce = -bcesum * inv;
            const float mr  =  coh_load(ws + 0) * inv;
            const float ms  =  mssum / (float)BATCH;
            out[0] = bce + ALPHA * mr + BETA * ms;
            out[1] = bce;
            out[2] = mr;
            out[3] = ms;
        }
    }
}

extern "C" void kernel_launch(void* const* d_in, const int* in_sizes, int n_in,
                              void* d_out, int out_size, void* d_ws, size_t ws_size,
                              hipStream_t stream) {
    const float* pred       = (const float*)d_in[0];
    const float* membership = (const float*)d_in[1];
    const float* moebius    = (const float*)d_in[2];
    const int*   tidx       = (const int*)d_in[3];
    float* out = (float*)d_out;
    float* ws  = (float*)d_ws;
    unsigned short* pred_bf = (unsigned short*)((char*)d_ws + WS_PREDBF_OFF);
    unsigned short* moeb_bf = (unsigned short*)((char*)d_ws + WS_MOEBBF_OFF);

    bce_convert_kernel<<<2048 + 64, 256, 0, stream>>>(
        pred, membership, tidx, moebius, ws, pred_bf, moeb_bf);
    masses_mfma_kernel<<<dim3(NSETS / BN, BATCH / BM), 256, 0, stream>>>(
        pred_bf, moeb_bf, ws, out);
}

// Round 6
// 173.000 us; speedup vs baseline: 1.2537x; 1.0080x over previous
//
#include <hip/hip_runtime.h>
#include <math.h>

#define BATCH 16384
#define NSETS 1024
#define ALPHA 0.001f
#define BETA  0.001f

// MFMA GEMM tile: 128x128 block, BK=64, 256 threads (4 waves, 2x2 wave grid,
// each wave 64x64 = 4x4 grid of 16x16x32 bf16 MFMA tiles, 2 k-steps per iter)
#define BM 128
#define BN 128
#define BK 64
#define NSTRIPE (BATCH / BM)            // 128 m-stripes
#define NBLK_N  (NSETS / BN)            // 8 n-blocks per stripe
#define GEMM_BLOCKS (NSTRIPE * NBLK_N)  // 1024

typedef __attribute__((ext_vector_type(4))) float f32x4;
typedef __attribute__((ext_vector_type(8))) __bf16 bf16x8;

// ws float-index layout:
//   [0] mr_sum  [1] global counter (uint)  [2] ms_sum  [3] pad
//   [4 .. 4+16384)           row sums (device-scope atomics)
//   [16388 .. 16388+2048)    bce per-block partials (write-once, prev dispatch)
//   [18436 .. 18436+128)     per-stripe completion counters (uint)
// ws byte layout:
//   [131072 ..)              pred_bf16 (33.5 MB)
//   [131072 + 33554432 ..)   moeb_bf16 (2 MB)
#define ROWSUM_OFF 4
#define BCEP_OFF   16388
#define STRIPE_OFF 18436
#define WS_PREDBF_OFF 131072
#define WS_MOEBBF_OFF (131072 + BATCH * NSETS * 2)

__device__ __forceinline__ unsigned short f2bf(float x) {
    unsigned int u = __builtin_bit_cast(unsigned int, x);
    u = (u + 0x7FFFu + ((u >> 16) & 1u)) >> 16;   // RNE (no NaN inputs here)
    return (unsigned short)u;
}

__device__ __forceinline__ void gld16(const void* g, void* l) {
    __builtin_amdgcn_global_load_lds(
        (const __attribute__((address_space(1))) unsigned int*)g,
        (__attribute__((address_space(3))) unsigned int*)l, 16, 0, 0);
}

// relaxed agent-scope load: bypasses (possibly stale) L1/L2, no cache inval
__device__ __forceinline__ float coh_load(const float* p) {
    return __hip_atomic_load(p, __ATOMIC_RELAXED, __HIP_MEMORY_SCOPE_AGENT);
}

__device__ __forceinline__ float block_reduce_sum(float v, float* sm) {
    #pragma unroll
    for (int off = 32; off > 0; off >>= 1) v += __shfl_down(v, off, 64);
    const int lane = threadIdx.x & 63;
    const int wid  = threadIdx.x >> 6;
    if (lane == 0) sm[wid] = v;
    __syncthreads();
    const int nw = blockDim.x >> 6;
    v = (threadIdx.x < nw) ? sm[threadIdx.x] : 0.0f;
    if (wid == 0) {
        #pragma unroll
        for (int off = 32; off > 0; off >>= 1) v += __shfl_down(v, off, 64);
    }
    return v;  // valid in thread 0
}

// -------- BCE (+ pred->bf16 convert + accumulator zeroing; blocks >= 2048
// convert moebius). Replaces the memset node.
__global__ __launch_bounds__(256)
void bce_convert_kernel(const float* __restrict__ pred,
                        const float* __restrict__ membership,
                        const int*   __restrict__ tidx,
                        const float* __restrict__ moeb,
                        float*       __restrict__ ws,
                        unsigned short* __restrict__ pred_bf,
                        unsigned short* __restrict__ moeb_bf) {
    const int tid = threadIdx.x;
    const int bi  = blockIdx.x;
    if (bi >= 2048) {   // moebius fp32->bf16: 64 blocks, 16 float4/thread
        const int base = (bi - 2048) * 4096 + tid;
        #pragma unroll
        for (int k = 0; k < 16; k++) {
            const int i = base + k * 256;
            const float4 v = ((const float4*)moeb)[i];
            ushort4 u;
            u.x = f2bf(v.x); u.y = f2bf(v.y); u.z = f2bf(v.z); u.w = f2bf(v.w);
            ((ushort4*)moeb_bf)[i] = u;
        }
        return;
    }
    // zero accumulators for the masses kernel (stream order guarantees vis.)
    if (tid < 8)                         ws[ROWSUM_OFF + bi * 8 + tid] = 0.0f;
    if (bi == 0 && tid >= 8 && tid < 12) ws[tid - 8] = 0.0f;
    if (bi == 1 && tid < NSTRIPE)        ws[STRIPE_OFF + tid] = 0.0f;

    __shared__ float sm[4];
    const float eps = 1e-7f;
    const float hi  = 1.0f - 1e-7f;
    float acc = 0.0f;
    const int base = bi * 256 + tid;          // 0..524287
    #pragma unroll
    for (int k = 0; k < 8; k++) {             // N4 = 4194304 = 8 * 524288
        const int i  = base + k * 524288;
        const int b  = i >> 8;                // row (256 float4 per row)
        const int s4 = i & 255;
        const float4 p4 = ((const float4*)pred)[i];
        const int cls   = tidx[b];
        const float4 t4 = ((const float4*)membership)[(cls << 8) + s4];
        float cp[4];
        cp[0] = fminf(fmaxf(p4.x, eps), hi);
        cp[1] = fminf(fmaxf(p4.y, eps), hi);
        cp[2] = fminf(fmaxf(p4.z, eps), hi);
        cp[3] = fminf(fmaxf(p4.w, eps), hi);
        ushort4 u;
        u.x = f2bf(cp[0]); u.y = f2bf(cp[1]); u.z = f2bf(cp[2]); u.w = f2bf(cp[3]);
        ((ushort4*)pred_bf)[i] = u;
        const float ts[4] = {t4.x, t4.y, t4.z, t4.w};
        #pragma unroll
        for (int j = 0; j < 4; j++) {
            const float x = (ts[j] > 0.5f) ? cp[j] : (1.0f - cp[j]);
            acc += __logf(x);
        }
    }
    const float tot = block_reduce_sum(acc, sm);
    if (tid == 0) ws[BCEP_OFF + bi] = tot;    // write-once partial
}

// -------- masses = p_bf16 @ moeb_bf16^T via MFMA; fused relu(-m) and row
// sums; hierarchical fence-free finalize (stripe-last -> global-last).
// XCD swizzle: block i -> XCD i%8 (CP round-robin); group all 8 n-blocks of
// an m-stripe onto ONE XCD so the A-panel is fetched into its L2 once.
// LDS layout: 16B chunk (row r, k-subchunk k8) stored at slot 8*r + (k8^(r&7))
// (global-side swizzle: gld16 forces LDS dest = base + lane*16).
__global__ __launch_bounds__(256)
void masses_mfma_kernel(const unsigned short* __restrict__ A,   // pred_bf [BATCH, NSETS]
                        const unsigned short* __restrict__ Bm,  // moeb_bf [NSETS, NSETS]
                        float* __restrict__ ws,
                        float* __restrict__ out) {
    __shared__ __align__(16) unsigned short Alds[BM * BK];  // 16 KB
    __shared__ __align__(16) unsigned short Blds[BN * BK];  // 16 KB
    __shared__ float rowacc[BM];
    __shared__ float sm[4];
    __shared__ unsigned flag;

    const int tid  = threadIdx.x;
    const int lane = tid & 63;
    const int w    = tid >> 6;
    const int wm   = w >> 1;
    const int wn   = w & 1;
    const int lr   = lane & 15;
    const int q    = lane >> 4;

    // XCD-aware swizzle (performance heuristic only)
    const int id     = blockIdx.x;
    const int xcd    = id & 7;
    const int slot   = id >> 3;               // 0..127 within XCD
    const int stripe = xcd * 16 + (slot >> 3); // 16 stripes per XCD
    const int nblk   = slot & 7;
    const int m0     = stripe * BM;
    const int n0     = nblk * BN;

    if (tid < BM) rowacc[tid] = 0.0f;

    f32x4 acc[4][4];
    #pragma unroll
    for (int i = 0; i < 4; i++)
        #pragma unroll
        for (int j = 0; j < 4; j++) acc[i][j] = (f32x4){0.f, 0.f, 0.f, 0.f};

    // staging: 1024 chunks of 16B per tile; thread t covers slots t+j*256.
    // slot s -> row r=s>>3, stored k8' = s&7, global k8 = k8' ^ (r&7)
    size_t aoff[4], boff[4];
    unsigned short *lA[4], *lB[4];
    #pragma unroll
    for (int j = 0; j < 4; j++) {
        const int s   = tid + j * 256;
        const int r   = s >> 3;
        const int gk8 = (s & 7) ^ (r & 7);
        aoff[j] = (size_t)(m0 + r) * NSETS + gk8 * 8;
        boff[j] = (size_t)(n0 + r) * NSETS + gk8 * 8;
        lA[j] = &Alds[s * 8];
        lB[j] = &Blds[s * 8];
    }
    const int sw = lr & 7;  // fragment-read swizzle term

    for (int k0 = 0; k0 < NSETS; k0 += BK) {
        #pragma unroll
        for (int j = 0; j < 4; j++) {
            gld16(A  + aoff[j] + k0, lA[j]);
            gld16(Bm + boff[j] + k0, lB[j]);
        }
        __syncthreads();

        #pragma unroll
        for (int h = 0; h < 2; h++) {
            bf16x8 a[4], b[4];
            const int hq = h * 4 + q;
            #pragma unroll
            for (int mi = 0; mi < 4; mi++)
                a[mi] = *(const bf16x8*)&Alds[(wm * 64 + mi * 16 + lr) * BK + 8 * (hq ^ sw)];
            #pragma unroll
            for (int ni = 0; ni < 4; ni++)
                b[ni] = *(const bf16x8*)&Blds[(wn * 64 + ni * 16 + lr) * BK + 8 * (hq ^ sw)];
            #pragma unroll
            for (int mi = 0; mi < 4; mi++)
                #pragma unroll
                for (int ni = 0; ni < 4; ni++)
                    acc[mi][ni] = __builtin_amdgcn_mfma_f32_16x16x32_bf16(
                        a[mi], b[ni], acc[mi][ni], 0, 0, 0);
        }
        __syncthreads();
    }

    // Epilogue. C/D layout: col = lane&15, row_in_tile = q*4 + r
    float mrpart = 0.0f;
    float rs[4][4];
    #pragma unroll
    for (int mi = 0; mi < 4; mi++)
        #pragma unroll
        for (int r = 0; r < 4; r++) rs[mi][r] = 0.0f;
    #pragma unroll
    for (int mi = 0; mi < 4; mi++)
        #pragma unroll
        for (int ni = 0; ni < 4; ni++)
            #pragma unroll
            for (int r = 0; r < 4; r++) {
                const float m = acc[mi][ni][r];
                mrpart    += fmaxf(-m, 0.0f);
                rs[mi][r] += m;
            }
    #pragma unroll
    for (int mi = 0; mi < 4; mi++)
        #pragma unroll
        for (int r = 0; r < 4; r++) {
            float v = rs[mi][r];
            #pragma unroll
            for (int off = 1; off < 16; off <<= 1) v += __shfl_xor(v, off, 16);
            if (lr == 0)
                atomicAdd(&rowacc[wm * 64 + mi * 16 + q * 4 + r], v);
        }

    const float mrtot = block_reduce_sum(mrpart, sm);  // has a barrier inside
    if (tid == 0) atomicAdd(&ws[0], mrtot);            // device-scope atomic
    __syncthreads();   // rowacc complete
    if (tid < BM) atomicAdd(&ws[ROWSUM_OFF + m0 + tid], rowacc[tid]);

    // ---- stage 1: stripe-last reduces |rowsum-1| for its 128 rows ----
    // __syncthreads drains vmcnt(0) per wave -> this block's atomics are at
    // the coherent point before the counter bump (fence-free, validated R5).
    __syncthreads();
    if (tid == 0)
        flag = (__hip_atomic_fetch_add((unsigned int*)&ws[STRIPE_OFF + stripe],
                    1u, __ATOMIC_RELAXED, __HIP_MEMORY_SCOPE_AGENT)
                == NBLK_N - 1);
    __syncthreads();
    if (flag) {
        float s_ms = 0.0f;
        if (tid < BM) {
            const float v = coh_load(ws + ROWSUM_OFF + m0 + tid);
            s_ms = fabsf(v - 1.0f);
        }
        __syncthreads();                 // sm reuse guard
        const float mssum = block_reduce_sum(s_ms, sm);
        if (tid == 0) atomicAdd(&ws[2], mssum);
    }
    __syncthreads();   // drain the ms atomic before the global bump

    // ---- stage 2: global-last combines mr, ms, bce ----
    if (tid == 0)
        flag = (__hip_atomic_fetch_add((unsigned int*)&ws[1], 1u,
                    __ATOMIC_RELAXED, __HIP_MEMORY_SCOPE_AGENT)
                == GEMM_BLOCKS - 1);
    __syncthreads();
    if (flag) {
        float s_bce = 0.0f;
        #pragma unroll
        for (int k = 0; k < 2; k++) {    // prev-dispatch data: plain loads OK
            const float4 v = ((const float4*)(ws + BCEP_OFF))[tid + k * 256];
            s_bce += v.x + v.y + v.z + v.w;
        }
        __syncthreads();                 // sm reuse guard
        const float bcesum = block_reduce_sum(s_bce, sm);
        if (tid == 0) {
            const float inv = 1.0f / ((float)BATCH * (float)NSETS);
            const float bce = -bcesum * inv;
            const float mr  =  coh_load(ws + 0) * inv;
            const float ms  =  coh_load(ws + 2) / (float)BATCH;
            out[0] = bce + ALPHA * mr + BETA * ms;
            out[1] = bce;
            out[2] = mr;
            out[3] = ms;
        }
    }
}

extern "C" void kernel_launch(void* const* d_in, const int* in_sizes, int n_in,
                              void* d_out, int out_size, void* d_ws, size_t ws_size,
                              hipStream_t stream) {
    const float* pred       = (const float*)d_in[0];
    const float* membership = (const float*)d_in[1];
    const float* moebius    = (const float*)d_in[2];
    const int*   tidx       = (const int*)d_in[3];
    float* out = (float*)d_out;
    float* ws  = (float*)d_ws;
    unsigned short* pred_bf = (unsigned short*)((char*)d_ws + WS_PREDBF_OFF);
    unsigned short* moeb_bf = (unsigned short*)((char*)d_ws + WS_MOEBBF_OFF);

    bce_convert_kernel<<<2048 + 64, 256, 0, stream>>>(
        pred, membership, tidx, moebius, ws, pred_bf, moeb_bf);
    masses_mfma_kernel<<<GEMM_BLOCKS, 256, 0, stream>>>(
        pred_bf, moeb_bf, ws, out);
}